// Round 1
// baseline (369.943 us; speedup 1.0000x reference)
//
#include <hip/hip_runtime.h>

#define N_NODES 8192
#define D 256
#define B 8
#define MAXDEG 128

// ---------- bf16 helpers ----------
static __device__ __forceinline__ float bf2f(unsigned short u) {
    union { float f; unsigned int i; } v; v.i = ((unsigned int)u) << 16; return v.f;
}
static __device__ __forceinline__ unsigned short f2bf(float f) {
    union { float f; unsigned int i; } v; v.f = f;
    unsigned int r = v.i + 0x7FFFu + ((v.i >> 16) & 1u);   // round-nearest-even
    return (unsigned short)(r >> 16);
}

// ---------- K1: dedup edges -> CSR (deg + adjacency lists) ----------
__global__ __launch_bounds__(256) void build_csr(const int* __restrict__ edges,
        unsigned int* __restrict__ bitmask, int* __restrict__ deg,
        int* __restrict__ adj, int n_edges) {
    int i = blockIdx.x * 256 + threadIdx.x;
    if (i >= n_edges) return;
    int src = edges[2 * i];
    int dst = edges[2 * i + 1];
    unsigned int bitpos = (unsigned int)src * N_NODES + (unsigned int)dst;
    unsigned int bit = 1u << (bitpos & 31u);
    unsigned int old = atomicOr(&bitmask[bitpos >> 5], bit);
    if (!(old & bit)) {                 // first time this (src,dst) is seen
        int slot = atomicAdd(&deg[src], 1);
        if (slot < MAXDEG) adj[src * MAXDEG + slot] = dst;
    }
}

// ---------- K2: xW = x @ W  (fp32 compute, bf16 store) ----------
// M = B*N_NODES = 65536, K = 256, N = 256. Tile: 64 rows x 256 cols, BK = 32.
#define BM 64
#define BK 32
__global__ __launch_bounds__(256) void gemm_xw(const float* __restrict__ x,
        const float* __restrict__ W, unsigned short* __restrict__ xWb) {
    __shared__ float As[BM][BK];        // 8 KB
    __shared__ float Ws[BK][D];         // 32 KB
    const int t = threadIdx.x;
    const int m0 = blockIdx.x * BM;
    const int r0 = (t >> 6) * 16;       // 4 wave-groups x 16 rows
    const int c4 = t & 63;              // float4 column group

    float4 acc[16];
#pragma unroll
    for (int r = 0; r < 16; ++r) acc[r] = make_float4(0.f, 0.f, 0.f, 0.f);

    for (int k0 = 0; k0 < D; k0 += BK) {
        // stage A tile: 64x32 floats
#pragma unroll
        for (int p = 0; p < 2; ++p) {
            int idx = p * 256 + t;
            int row = idx >> 3, cc = idx & 7;
            *(float4*)&As[row][cc * 4] =
                *(const float4*)&x[(size_t)(m0 + row) * D + k0 + cc * 4];
        }
        // stage W tile: 32x256 floats
#pragma unroll
        for (int p = 0; p < 8; ++p) {
            int idx = p * 256 + t;
            int row = idx >> 6, cc = idx & 63;
            *(float4*)&Ws[row][cc * 4] =
                *(const float4*)&W[(size_t)(k0 + row) * D + cc * 4];
        }
        __syncthreads();
#pragma unroll
        for (int kk = 0; kk < BK; ++kk) {
            float4 w4 = *(const float4*)&Ws[kk][c4 * 4];
#pragma unroll
            for (int r = 0; r < 16; ++r) {
                float a = As[r0 + r][kk];       // wave-uniform -> LDS broadcast
                acc[r].x += a * w4.x; acc[r].y += a * w4.y;
                acc[r].z += a * w4.z; acc[r].w += a * w4.w;
            }
        }
        __syncthreads();
    }
#pragma unroll
    for (int r = 0; r < 16; ++r) {
        ushort4 o;
        o.x = f2bf(acc[r].x); o.y = f2bf(acc[r].y);
        o.z = f2bf(acc[r].z); o.w = f2bf(acc[r].w);
        *(ushort4*)&xWb[(size_t)(m0 + r0 + r) * D + c4 * 4] = o;
    }
}

// ---------- K3: h[b,n,:] = sum_{m in adj(n)} xW[b,m,:]; LeakyReLU; LayerNorm ----------
// One block per node n (512 threads = 8 waves = 8 batches). Lane covers 4 cols.
__global__ __launch_bounds__(512) void gather_ln(const unsigned short* __restrict__ xWb,
        const int* __restrict__ deg, const int* __restrict__ adj,
        const float* __restrict__ gamma, const float* __restrict__ beta,
        float* __restrict__ out) {
    const int n = blockIdx.x;
    const int tid = threadIdx.x;
    const int w = tid >> 6;             // batch index
    const int lane = tid & 63;

    __shared__ int nbr[MAXDEG];
    __shared__ int sdeg;
    if (tid == 0) {
        int dgv = deg[n];
        sdeg = dgv > MAXDEG ? MAXDEG : dgv;
    }
    __syncthreads();
    const int dg = sdeg;
    for (int i = tid; i < dg; i += 512) nbr[i] = adj[n * MAXDEG + i];
    __syncthreads();

    float4 acc = make_float4(0.f, 0.f, 0.f, 0.f);
    const unsigned short* base = xWb + (size_t)w * N_NODES * D + lane * 4;
#pragma unroll 2
    for (int i = 0; i < dg; ++i) {
        ushort4 v = *(const ushort4*)(base + (size_t)nbr[i] * D);
        acc.x += bf2f(v.x); acc.y += bf2f(v.y);
        acc.z += bf2f(v.z); acc.w += bf2f(v.w);
    }
    // LeakyReLU(0.1)
    acc.x = acc.x >= 0.f ? acc.x : 0.1f * acc.x;
    acc.y = acc.y >= 0.f ? acc.y : 0.1f * acc.y;
    acc.z = acc.z >= 0.f ? acc.z : 0.1f * acc.z;
    acc.w = acc.w >= 0.f ? acc.w : 0.1f * acc.w;
    // LayerNorm over the 256 values held by this wave (4 per lane)
    float s = acc.x + acc.y + acc.z + acc.w;
    float q = acc.x * acc.x + acc.y * acc.y + acc.z * acc.z + acc.w * acc.w;
#pragma unroll
    for (int off = 1; off < 64; off <<= 1) {
        s += __shfl_xor(s, off);
        q += __shfl_xor(q, off);
    }
    const float mean = s * (1.f / D);
    const float var  = q * (1.f / D) - mean * mean;
    const float rstd = rsqrtf(var + 1e-5f);
    float4 g  = *(const float4*)(gamma + lane * 4);
    float4 bt = *(const float4*)(beta + lane * 4);
    float4 o;
    o.x = g.x * (acc.x - mean) * rstd + bt.x;
    o.y = g.y * (acc.y - mean) * rstd + bt.y;
    o.z = g.z * (acc.z - mean) * rstd + bt.z;
    o.w = g.w * (acc.w - mean) * rstd + bt.w;
    *(float4*)(out + ((size_t)w * N_NODES + n) * D + lane * 4) = o;
}

// ---------- launch ----------
extern "C" void kernel_launch(void* const* d_in, const int* in_sizes, int n_in,
                              void* d_out, int out_size, void* d_ws, size_t ws_size,
                              hipStream_t stream) {
    const float* x     = (const float*)d_in[0];
    const float* W     = (const float*)d_in[1];
    const float* gamma = (const float*)d_in[2];
    const float* beta  = (const float*)d_in[3];
    const int*   edges = (const int*)d_in[4];
    const int n_edges  = in_sizes[4] / 2;

    char* ws = (char*)d_ws;
    int*          degp    = (int*)ws;                                   // 32 KB
    unsigned int* bitmask = (unsigned int*)(ws + 32768);                // 8 MB
    int*          adj     = (int*)(ws + 32768 + 8388608);               // 4 MB
    unsigned short* xWb   = (unsigned short*)(ws + 32768 + 8388608 + 4194304); // 32 MB

    // zero deg + bitmask (ws is re-poisoned to 0xAA before every launch)
    hipMemsetAsync(d_ws, 0, 32768 + 8388608, stream);

    build_csr<<<(n_edges + 255) / 256, 256, 0, stream>>>(edges, bitmask, degp, adj, n_edges);
    gemm_xw<<<(B * N_NODES) / BM, 256, 0, stream>>>(x, W, xWb);
    gather_ln<<<N_NODES, 512, 0, stream>>>(xWb, degp, adj, gamma, beta, (float*)d_out);
}

// Round 5
// 244.804 us; speedup vs baseline: 1.5112x; 1.5112x over previous
//
#include <hip/hip_runtime.h>

#define N_NODES 8192
#define D 256
#define B 8
#define MAXDEG 128

typedef __attribute__((ext_vector_type(8))) short bf16x8;
typedef __attribute__((ext_vector_type(4))) float f32x4;

// ---------- bf16 helpers ----------
static __device__ __forceinline__ float bf2f(unsigned short u) {
    union { float f; unsigned int i; } v; v.i = ((unsigned int)u) << 16; return v.f;
}
static __device__ __forceinline__ unsigned short f2bf(float f) {
    union { float f; unsigned int i; } v; v.f = f;
    unsigned int r = v.i + 0x7FFFu + ((v.i >> 16) & 1u);   // round-nearest-even
    return (unsigned short)(r >> 16);
}

// ---------- K1: dedup edges -> CSR (deg + adjacency lists) ----------
__global__ __launch_bounds__(256) void build_csr(const int* __restrict__ edges,
        unsigned int* __restrict__ bitmask, int* __restrict__ deg,
        int* __restrict__ adj, int n_edges) {
    int i = blockIdx.x * 256 + threadIdx.x;
    if (i >= n_edges) return;
    int src = edges[2 * i];
    int dst = edges[2 * i + 1];
    unsigned int bitpos = (unsigned int)src * N_NODES + (unsigned int)dst;
    unsigned int bit = 1u << (bitpos & 31u);
    unsigned int old = atomicOr(&bitmask[bitpos >> 5], bit);
    if (!(old & bit)) {                 // first time this (src,dst) is seen
        int slot = atomicAdd(&deg[src], 1);
        if (slot < MAXDEG) adj[src * MAXDEG + slot] = dst;
    }
}

// ---------- K2a: W (fp32 [k][n]) -> Wt (bf16 [n][k]) ----------
__global__ __launch_bounds__(256) void convert_wt(const float* __restrict__ W,
        unsigned short* __restrict__ Wt) {
    int idx = blockIdx.x * 256 + threadIdx.x;     // 65536 total
    int n = idx >> 8, k = idx & 255;
    Wt[n * 256 + k] = f2bf(W[k * 256 + n]);
}

// ---------- K2b: xWb = bf16(x) @ bf16(W), MFMA, bf16 out ----------
// M=65536, K=256, N=256. Block: 128 rows x all 256 cols, 512 thr (8 waves 2x4),
// wave tile 64x64, mfma_f32_16x16x32_bf16 swapped-operand (D cols = m, rows = n).
#define GBM 128
__global__ __launch_bounds__(512) void gemm_mfma(const float* __restrict__ x,
        const unsigned short* __restrict__ Wt, unsigned short* __restrict__ xWb) {
    __shared__ alignas(16) char AsB[128 * 128];       // 128 rows x 64 bf16 (swizzled)
    __shared__ alignas(16) char WsB[256 * 128];       // 256 rows x 64 bf16 (swizzled)
    const int t = threadIdx.x;
    const int l = t & 63;
    const int w = t >> 6;
    const int wr = w >> 2;          // 0..1  (m-quadrant)
    const int wc = w & 3;           // 0..3  (n-quadrant)
    const size_t m0 = (size_t)blockIdx.x * GBM;

    f32x4 acc[4][4];
#pragma unroll
    for (int i = 0; i < 4; ++i)
#pragma unroll
        for (int j = 0; j < 4; ++j) acc[i][j] = (f32x4){0.f, 0.f, 0.f, 0.f};

    for (int ks = 0; ks < 4; ++ks) {
        const int k0 = ks * 64;
        // ---- stage A: x fp32 -> bf16, XOR-swizzled LDS (T2) ----
#pragma unroll
        for (int p = 0; p < 4; ++p) {
            const int row = p * 32 + (t >> 4);
            const int c4  = t & 15;
            float4 v = *(const float4*)&x[(m0 + row) * 256 + k0 + c4 * 4];
            uint2 pk;
            pk.x = (unsigned)f2bf(v.x) | ((unsigned)f2bf(v.y) << 16);
            pk.y = (unsigned)f2bf(v.z) | ((unsigned)f2bf(v.w) << 16);
            const int g = c4 >> 1;                 // 16B granule 0..7
            *(uint2*)&AsB[row * 128 + ((g ^ (row & 7)) * 16) + (c4 & 1) * 8] = pk;
        }
        // ---- stage W: global_load_lds 16B, swizzle folded into SOURCE addr ----
#pragma unroll
        for (int p = 0; p < 4; ++p) {
            const int rp = p * 64 + w * 8 + (l >> 3);
            const int sg = (l & 7) ^ (rp & 7);     // pre-swizzled source granule
            const unsigned short* gp = Wt + rp * 256 + k0 + sg * 8;
            char* lp = &WsB[p * 8192 + w * 1024];  // wave-uniform; HW adds lane*16
            __builtin_amdgcn_global_load_lds(
                (__attribute__((address_space(1))) unsigned int*)gp,
                (__attribute__((address_space(3))) unsigned int*)lp, 16, 0, 0);
        }
        __syncthreads();
        // ---- compute: 2 k-chunks x 16 MFMA ----
#pragma unroll
        for (int kc = 0; kc < 2; ++kc) {
            bf16x8 xa[4], wb[4];
#pragma unroll
            for (int fm = 0; fm < 4; ++fm) {
                const int row = wr * 64 + fm * 16 + (l & 15);
                const int g = kc * 4 + (l >> 4);
                xa[fm] = *(const bf16x8*)&AsB[row * 128 + ((g ^ (row & 7)) * 16)];
            }
#pragma unroll
            for (int fn = 0; fn < 4; ++fn) {
                const int n = wc * 64 + fn * 16 + (l & 15);
                const int g = kc * 4 + (l >> 4);
                wb[fn] = *(const bf16x8*)&WsB[n * 128 + ((g ^ (n & 7)) * 16)];
            }
#pragma unroll
            for (int fm = 0; fm < 4; ++fm)
#pragma unroll
                for (int fn = 0; fn < 4; ++fn)
                    acc[fm][fn] = __builtin_amdgcn_mfma_f32_16x16x32_bf16(
                        wb[fn], xa[fm], acc[fm][fn], 0, 0, 0);
        }
        __syncthreads();
    }
    // ---- epilogue: lane holds 4 consecutive n -> packed 8B stores ----
#pragma unroll
    for (int fm = 0; fm < 4; ++fm) {
        const size_t m = m0 + wr * 64 + fm * 16 + (l & 15);
        unsigned short* rowp = xWb + m * 256 + wc * 64 + (l >> 4) * 4;
#pragma unroll
        for (int fn = 0; fn < 4; ++fn) {
            f32x4 v = acc[fm][fn];
            uint2 pk;
            pk.x = (unsigned)f2bf(v.x) | ((unsigned)f2bf(v.y) << 16);
            pk.y = (unsigned)f2bf(v.z) | ((unsigned)f2bf(v.w) << 16);
            *(uint2*)(rowp + fn * 16) = pk;
        }
    }
}

// ---------- K3: gather + LeakyReLU + LayerNorm, XCD-pinned per batch ----------
// block = (batch = bid&7, 8 nodes), 512 thr = 8 waves, wave = one (node,batch).
// XCD k (round-robin dispatch) only touches batch k's 4MB xWb slab -> L2-resident.
__global__ __launch_bounds__(512) void gather_ln(const unsigned short* __restrict__ xWb,
        const int* __restrict__ deg, const int* __restrict__ adj,
        const float* __restrict__ gamma, const float* __restrict__ beta,
        float* __restrict__ out) {
    const int bid = blockIdx.x;
    const int batch = bid & 7;
    const int w = threadIdx.x >> 6;
    const int l = threadIdx.x & 63;
    const int n = (bid >> 3) * 8 + w;

    __shared__ int nbr[8][MAXDEG];
    int dg = __builtin_nontemporal_load(&deg[n]);
    dg = dg > MAXDEG ? MAXDEG : dg;
    for (int i = l; i < dg; i += 64)
        nbr[w][i] = __builtin_nontemporal_load(&adj[n * MAXDEG + i]);
    __syncthreads();

    const unsigned short* base = xWb + (size_t)batch * (N_NODES * D) + l * 4;
    float4 acc = make_float4(0.f, 0.f, 0.f, 0.f);
    int i = 0;
    for (; i + 4 <= dg; i += 4) {
        int4 r = *(const int4*)&nbr[w][i];
        ushort4 v0 = *(const ushort4*)(base + (size_t)r.x * D);
        ushort4 v1 = *(const ushort4*)(base + (size_t)r.y * D);
        ushort4 v2 = *(const ushort4*)(base + (size_t)r.z * D);
        ushort4 v3 = *(const ushort4*)(base + (size_t)r.w * D);
        acc.x += (bf2f(v0.x) + bf2f(v1.x)) + (bf2f(v2.x) + bf2f(v3.x));
        acc.y += (bf2f(v0.y) + bf2f(v1.y)) + (bf2f(v2.y) + bf2f(v3.y));
        acc.z += (bf2f(v0.z) + bf2f(v1.z)) + (bf2f(v2.z) + bf2f(v3.z));
        acc.w += (bf2f(v0.w) + bf2f(v1.w)) + (bf2f(v2.w) + bf2f(v3.w));
    }
    for (; i < dg; ++i) {
        ushort4 v = *(const ushort4*)(base + (size_t)nbr[w][i] * D);
        acc.x += bf2f(v.x); acc.y += bf2f(v.y);
        acc.z += bf2f(v.z); acc.w += bf2f(v.w);
    }
    // LeakyReLU(0.1)
    acc.x = acc.x >= 0.f ? acc.x : 0.1f * acc.x;
    acc.y = acc.y >= 0.f ? acc.y : 0.1f * acc.y;
    acc.z = acc.z >= 0.f ? acc.z : 0.1f * acc.z;
    acc.w = acc.w >= 0.f ? acc.w : 0.1f * acc.w;
    // LayerNorm over the wave's 256 values (4/lane)
    float s = acc.x + acc.y + acc.z + acc.w;
    float q = acc.x * acc.x + acc.y * acc.y + acc.z * acc.z + acc.w * acc.w;
#pragma unroll
    for (int off = 1; off < 64; off <<= 1) {
        s += __shfl_xor(s, off);
        q += __shfl_xor(q, off);
    }
    const float mean = s * (1.f / D);
    const float var  = q * (1.f / D) - mean * mean;
    const float rstd = rsqrtf(var + 1e-5f);
    float4 g  = *(const float4*)(gamma + l * 4);
    float4 bt = *(const float4*)(beta + l * 4);
    f32x4 o;
    o.x = g.x * (acc.x - mean) * rstd + bt.x;
    o.y = g.y * (acc.y - mean) * rstd + bt.y;
    o.z = g.z * (acc.z - mean) * rstd + bt.z;
    o.w = g.w * (acc.w - mean) * rstd + bt.w;
    // nontemporal builtin needs a clang ext_vector pointer, not HIP float4
    __builtin_nontemporal_store(o,
        (f32x4*)(out + ((size_t)batch * N_NODES + n) * D + l * 4));
}

// ---------- launch ----------
extern "C" void kernel_launch(void* const* d_in, const int* in_sizes, int n_in,
                              void* d_out, int out_size, void* d_ws, size_t ws_size,
                              hipStream_t stream) {
    const float* x     = (const float*)d_in[0];
    const float* W     = (const float*)d_in[1];
    const float* gamma = (const float*)d_in[2];
    const float* beta  = (const float*)d_in[3];
    const int*   edges = (const int*)d_in[4];
    const int n_edges  = in_sizes[4] / 2;

    char* ws = (char*)d_ws;
    int*            degp    = (int*)ws;                                    // 32 KB
    unsigned int*   bitmask = (unsigned int*)(ws + 32768);                 // 8 MB
    int*            adj     = (int*)(ws + 32768 + 8388608);                // 4 MB
    unsigned short* xWb     = (unsigned short*)(ws + 32768 + 8388608 + 4194304); // 32 MB
    // Wt aliases the bitmask region: written only AFTER build_csr is done
    unsigned short* Wt      = (unsigned short*)(ws + 32768);               // 128 KB

    (void)hipMemsetAsync(d_ws, 0, 32768 + 8388608, stream);   // zero deg + bitmask

    build_csr<<<(n_edges + 255) / 256, 256, 0, stream>>>(edges, bitmask, degp, adj, n_edges);
    convert_wt<<<256, 256, 0, stream>>>(W, Wt);          // after build_csr (aliases bitmask)
    gemm_mfma<<<(B * N_NODES) / GBM, 512, 0, stream>>>(x, Wt, xWb);
    gather_ln<<<N_NODES, 512, 0, stream>>>(xWb, degp, adj, gamma, beta, (float*)d_out);
}

// Round 6
// 221.363 us; speedup vs baseline: 1.6712x; 1.1059x over previous
//
#include <hip/hip_runtime.h>

#define N_NODES 8192
#define D 256
#define B 8
#define MAXDEG 128

typedef __attribute__((ext_vector_type(8))) short bf16x8;
typedef __attribute__((ext_vector_type(4))) float f32x4;
typedef __attribute__((ext_vector_type(4))) unsigned int u32x4;

// ---------- bf16 helpers ----------
static __device__ __forceinline__ float bf2f(unsigned short u) {
    union { float f; unsigned int i; } v; v.i = ((unsigned int)u) << 16; return v.f;
}
static __device__ __forceinline__ float bflo(unsigned int u) {       // low bf16 of a packed u32
    union { float f; unsigned int i; } v; v.i = u << 16; return v.f;
}
static __device__ __forceinline__ float bfhi(unsigned int u) {       // high bf16 of a packed u32
    union { float f; unsigned int i; } v; v.i = u & 0xFFFF0000u; return v.f;
}
static __device__ __forceinline__ unsigned short f2bf(float f) {
    union { float f; unsigned int i; } v; v.f = f;
    unsigned int r = v.i + 0x7FFFu + ((v.i >> 16) & 1u);   // round-nearest-even
    return (unsigned short)(r >> 16);
}

// ---------- K1: dedup edges -> CSR (deg + adjacency lists) ----------
__global__ __launch_bounds__(256) void build_csr(const int* __restrict__ edges,
        unsigned int* __restrict__ bitmask, int* __restrict__ deg,
        int* __restrict__ adj, int n_edges) {
    int i = blockIdx.x * 256 + threadIdx.x;
    if (i >= n_edges) return;
    int src = edges[2 * i];
    int dst = edges[2 * i + 1];
    unsigned int bitpos = (unsigned int)src * N_NODES + (unsigned int)dst;
    unsigned int bit = 1u << (bitpos & 31u);
    unsigned int old = atomicOr(&bitmask[bitpos >> 5], bit);
    if (!(old & bit)) {                 // first time this (src,dst) is seen
        int slot = atomicAdd(&deg[src], 1);
        if (slot < MAXDEG) adj[src * MAXDEG + slot] = dst;
    }
}

// ---------- K2a: W (fp32 [k][n]) -> Wt (bf16 [n][k]) ----------
__global__ __launch_bounds__(256) void convert_wt(const float* __restrict__ W,
        unsigned short* __restrict__ Wt) {
    int idx = blockIdx.x * 256 + threadIdx.x;     // 65536 total
    int n = idx >> 8, k = idx & 255;
    Wt[n * 256 + k] = f2bf(W[k * 256 + n]);
}

// ---------- K2b: xWb = bf16(x) @ bf16(W), MFMA, bf16 out ----------
// M=65536, K=256, N=256. Block: 128 rows x all 256 cols, 512 thr (8 waves 2x4),
// wave tile 64x64, mfma_f32_16x16x32_bf16 swapped-operand (D cols = m, rows = n).
#define GBM 128
__global__ __launch_bounds__(512) void gemm_mfma(const float* __restrict__ x,
        const unsigned short* __restrict__ Wt, unsigned short* __restrict__ xWb) {
    __shared__ alignas(16) char AsB[128 * 128];       // 128 rows x 64 bf16 (swizzled)
    __shared__ alignas(16) char WsB[256 * 128];       // 256 rows x 64 bf16 (swizzled)
    const int t = threadIdx.x;
    const int l = t & 63;
    const int w = t >> 6;
    const int wr = w >> 2;          // 0..1  (m-quadrant)
    const int wc = w & 3;           // 0..3  (n-quadrant)
    const size_t m0 = (size_t)blockIdx.x * GBM;

    f32x4 acc[4][4];
#pragma unroll
    for (int i = 0; i < 4; ++i)
#pragma unroll
        for (int j = 0; j < 4; ++j) acc[i][j] = (f32x4){0.f, 0.f, 0.f, 0.f};

    for (int ks = 0; ks < 4; ++ks) {
        const int k0 = ks * 64;
        // ---- stage A: x fp32 -> bf16, XOR-swizzled LDS (T2) ----
#pragma unroll
        for (int p = 0; p < 4; ++p) {
            const int row = p * 32 + (t >> 4);
            const int c4  = t & 15;
            float4 v = *(const float4*)&x[(m0 + row) * 256 + k0 + c4 * 4];
            uint2 pk;
            pk.x = (unsigned)f2bf(v.x) | ((unsigned)f2bf(v.y) << 16);
            pk.y = (unsigned)f2bf(v.z) | ((unsigned)f2bf(v.w) << 16);
            const int g = c4 >> 1;                 // 16B granule 0..7
            *(uint2*)&AsB[row * 128 + ((g ^ (row & 7)) * 16) + (c4 & 1) * 8] = pk;
        }
        // ---- stage W: global_load_lds 16B, swizzle folded into SOURCE addr ----
#pragma unroll
        for (int p = 0; p < 4; ++p) {
            const int rp = p * 64 + w * 8 + (l >> 3);
            const int sg = (l & 7) ^ (rp & 7);     // pre-swizzled source granule
            const unsigned short* gp = Wt + rp * 256 + k0 + sg * 8;
            char* lp = &WsB[p * 8192 + w * 1024];  // wave-uniform; HW adds lane*16
            __builtin_amdgcn_global_load_lds(
                (__attribute__((address_space(1))) unsigned int*)gp,
                (__attribute__((address_space(3))) unsigned int*)lp, 16, 0, 0);
        }
        __syncthreads();
        // ---- compute: 2 k-chunks x 16 MFMA ----
#pragma unroll
        for (int kc = 0; kc < 2; ++kc) {
            bf16x8 xa[4], wb[4];
#pragma unroll
            for (int fm = 0; fm < 4; ++fm) {
                const int row = wr * 64 + fm * 16 + (l & 15);
                const int g = kc * 4 + (l >> 4);
                xa[fm] = *(const bf16x8*)&AsB[row * 128 + ((g ^ (row & 7)) * 16)];
            }
#pragma unroll
            for (int fn = 0; fn < 4; ++fn) {
                const int n = wc * 64 + fn * 16 + (l & 15);
                const int g = kc * 4 + (l >> 4);
                wb[fn] = *(const bf16x8*)&WsB[n * 128 + ((g ^ (n & 7)) * 16)];
            }
#pragma unroll
            for (int fm = 0; fm < 4; ++fm)
#pragma unroll
                for (int fn = 0; fn < 4; ++fn)
                    acc[fm][fn] = __builtin_amdgcn_mfma_f32_16x16x32_bf16(
                        wb[fn], xa[fm], acc[fm][fn], 0, 0, 0);
        }
        __syncthreads();
    }
    // ---- epilogue: lane holds 4 consecutive n -> packed 8B stores ----
#pragma unroll
    for (int fm = 0; fm < 4; ++fm) {
        const size_t m = m0 + wr * 64 + fm * 16 + (l & 15);
        unsigned short* rowp = xWb + m * 256 + wc * 64 + (l >> 4) * 4;
#pragma unroll
        for (int fn = 0; fn < 4; ++fn) {
            f32x4 v = acc[fm][fn];
            uint2 pk;
            pk.x = (unsigned)f2bf(v.x) | ((unsigned)f2bf(v.y) << 16);
            pk.y = (unsigned)f2bf(v.z) | ((unsigned)f2bf(v.w) << 16);
            *(uint2*)(rowp + fn * 16) = pk;
        }
    }
}

// ---------- K3: gather + LeakyReLU + LayerNorm, XCD-pinned per batch ----------
// block = (batch = bid&7, 8 nodes), 512 thr = 8 waves, wave = one (node,batch).
// Half-wave scheme: lanes (half, sl): each half gathers a DIFFERENT neighbor row,
// 16B/lane x 32 lanes = full 512B row per half -> 2 neighbors per load instruction.
__global__ __launch_bounds__(512) void gather_ln(const unsigned short* __restrict__ xWb,
        const int* __restrict__ deg, const int* __restrict__ adj,
        const float* __restrict__ gamma, const float* __restrict__ beta,
        float* __restrict__ out) {
    const int bid = blockIdx.x;
    const int batch = bid & 7;
    const int w = threadIdx.x >> 6;
    const int l = threadIdx.x & 63;
    const int half = l >> 5;
    const int sl = l & 31;
    const int n = (bid >> 3) * 8 + w;

    __shared__ int off[8][MAXDEG];     // pre-shifted byte offsets
    int dg = deg[n];
    dg = dg > MAXDEG ? MAXDEG : dg;
    for (int i = l; i < dg; i += 64)
        off[w][i] = adj[n * MAXDEG + i] << 9;      // * D * sizeof(bf16) = 512
    __syncthreads();

    const char* base = (const char*)xWb + (size_t)batch * (N_NODES * D * 2) + sl * 16;
    f32x4 a0 = {0.f, 0.f, 0.f, 0.f}, a1 = {0.f, 0.f, 0.f, 0.f};
    int i = 0;
#pragma unroll 2
    for (; i + 2 <= dg; i += 2) {
        u32x4 v = *(const u32x4*)(base + off[w][i + half]);
        f32x4 c0, c1;
        c0.x = bflo(v.x); c0.y = bfhi(v.x); c0.z = bflo(v.y); c0.w = bfhi(v.y);
        c1.x = bflo(v.z); c1.y = bfhi(v.z); c1.z = bflo(v.w); c1.w = bfhi(v.w);
        a0 += c0;                       // vector add -> v_pk_add_f32
        a1 += c1;
    }
    if (i < dg && half == 0) {          // odd-degree tail: half 0 only
        u32x4 v = *(const u32x4*)(base + off[w][i]);
        f32x4 c0, c1;
        c0.x = bflo(v.x); c0.y = bfhi(v.x); c0.z = bflo(v.y); c0.w = bfhi(v.y);
        c1.x = bflo(v.z); c1.y = bfhi(v.z); c1.z = bflo(v.w); c1.w = bfhi(v.w);
        a0 += c0;
        a1 += c1;
    }
    // combine the two half-wave partial sums (lanes l and l^32 hold same 8 cols)
    a0.x += __shfl_xor(a0.x, 32); a0.y += __shfl_xor(a0.y, 32);
    a0.z += __shfl_xor(a0.z, 32); a0.w += __shfl_xor(a0.w, 32);
    a1.x += __shfl_xor(a1.x, 32); a1.y += __shfl_xor(a1.y, 32);
    a1.z += __shfl_xor(a1.z, 32); a1.w += __shfl_xor(a1.w, 32);
    // LeakyReLU(0.1) on the lane's 8 columns
    a0.x = a0.x >= 0.f ? a0.x : 0.1f * a0.x;
    a0.y = a0.y >= 0.f ? a0.y : 0.1f * a0.y;
    a0.z = a0.z >= 0.f ? a0.z : 0.1f * a0.z;
    a0.w = a0.w >= 0.f ? a0.w : 0.1f * a0.w;
    a1.x = a1.x >= 0.f ? a1.x : 0.1f * a1.x;
    a1.y = a1.y >= 0.f ? a1.y : 0.1f * a1.y;
    a1.z = a1.z >= 0.f ? a1.z : 0.1f * a1.z;
    a1.w = a1.w >= 0.f ? a1.w : 0.1f * a1.w;
    // LayerNorm stats: 8 values/lane, reduce across the 32-lane group
    float s = (a0.x + a0.y + a0.z + a0.w) + (a1.x + a1.y + a1.z + a1.w);
    float q = (a0.x * a0.x + a0.y * a0.y + a0.z * a0.z + a0.w * a0.w)
            + (a1.x * a1.x + a1.y * a1.y + a1.z * a1.z + a1.w * a1.w);
#pragma unroll
    for (int o = 1; o < 32; o <<= 1) {
        s += __shfl_xor(s, o);
        q += __shfl_xor(q, o);
    }
    const float mean = s * (1.f / D);
    const float var  = q * (1.f / D) - mean * mean;
    const float rstd = rsqrtf(var + 1e-5f);
    // each lane stores 4 cols: half0 -> sl*8, half1 -> sl*8+4
    f32x4 sel = half ? a1 : a0;
    const int col = sl * 8 + half * 4;
    float4 g  = *(const float4*)(gamma + col);
    float4 bt = *(const float4*)(beta + col);
    f32x4 o4;
    o4.x = g.x * (sel.x - mean) * rstd + bt.x;
    o4.y = g.y * (sel.y - mean) * rstd + bt.y;
    o4.z = g.z * (sel.z - mean) * rstd + bt.z;
    o4.w = g.w * (sel.w - mean) * rstd + bt.w;
    __builtin_nontemporal_store(o4,
        (f32x4*)(out + ((size_t)batch * N_NODES + n) * D + col));
}

// ---------- launch ----------
extern "C" void kernel_launch(void* const* d_in, const int* in_sizes, int n_in,
                              void* d_out, int out_size, void* d_ws, size_t ws_size,
                              hipStream_t stream) {
    const float* x     = (const float*)d_in[0];
    const float* W     = (const float*)d_in[1];
    const float* gamma = (const float*)d_in[2];
    const float* beta  = (const float*)d_in[3];
    const int*   edges = (const int*)d_in[4];
    const int n_edges  = in_sizes[4] / 2;

    char* ws = (char*)d_ws;
    int*            degp    = (int*)ws;                                    // 32 KB
    unsigned int*   bitmask = (unsigned int*)(ws + 32768);                 // 8 MB
    int*            adj     = (int*)(ws + 32768 + 8388608);                // 4 MB
    unsigned short* xWb     = (unsigned short*)(ws + 32768 + 8388608 + 4194304); // 32 MB
    // Wt aliases the bitmask region: written only AFTER build_csr is done
    unsigned short* Wt      = (unsigned short*)(ws + 32768);               // 128 KB

    (void)hipMemsetAsync(d_ws, 0, 32768 + 8388608, stream);   // zero deg + bitmask

    build_csr<<<(n_edges + 255) / 256, 256, 0, stream>>>(edges, bitmask, degp, adj, n_edges);
    convert_wt<<<256, 256, 0, stream>>>(W, Wt);          // after build_csr (aliases bitmask)
    gemm_mfma<<<(B * N_NODES) / GBM, 512, 0, stream>>>(x, Wt, xWb);
    gather_ln<<<N_NODES, 512, 0, stream>>>(xWb, degp, adj, gamma, beta, (float*)d_out);
}